// Round 1
// baseline (627.590 us; speedup 1.0000x reference)
//
#include <hip/hip_runtime.h>
#include <cstdint>
#include <cstddef>

// Top-1 MoE gate. s=8192, e=64, d=2048, cap=128.
// d_out (float32): [l_aux(1), combine(8192*64*128), mask(8192*64*128)]
// 3-kernel pipeline (zeroing split across k1..k2, balanced ~309 MB / ~308 MB HBM):
//   k1 gemm_zero_a   : 256 split-K GEMM blocks + 768 blocks zero region A
//   k2 reduce_scan_z : block 0 = scanner (spins on ctr==256, then ballot-rank
//                      scan -> loc[] + l_aux); blocks 1-256 reduce partials
//                      (softmax/argmax/gsum) then release ctr; 257-1024 zero B
//   k3 scatter       : 2 stores per surviving token into pre-zeroed output

#define S_TOK 8192
#define NEXP 64
#define DIM 2048
#define CAP 128
#define COMB_ELEMS ((size_t)S_TOK * NEXP * CAP)   // 67108864
#define OUT_ELEMS (1 + 2 * COMB_ELEMS)            // 134217729
#define NQUAD ((size_t)(OUT_ELEMS / 4))           // 33554432 quads cover all but last elem

// Region split chosen so k1 (zeros + 64MB x + 8MB P) ~= k2 (zeros + 8MB P) in HBM bytes.
#define QA ((size_t)14800000)   // region A: [0, QA)    ~236.8 MB (k1)
                                // region B: [QA, NQUAD) ~300.1 MB (k2)

#define TOK_TILE 128
#define NSLICE 4
#define KSLICE (DIM / NSLICE)   // 512
#define KC 32

__device__ __forceinline__ void zero_quads(float* __restrict__ out,
                                           size_t q_begin, size_t q_end,
                                           int nblocks, int bid) {
    const float4 z = { 0.0f, 0.0f, 0.0f, 0.0f };
    size_t stride = (size_t)nblocks * blockDim.x;
    for (size_t q = q_begin + (size_t)bid * blockDim.x + threadIdx.x;
         q < q_end; q += stride)
        *(float4*)(out + 4 * q) = z;
}

// ---------------------------------------------------------------------------
// Kernel 1: split-K logits GEMM (blocks 0-255) + zero region A (blocks 256-1023)
// ---------------------------------------------------------------------------
__global__ __launch_bounds__(256, 4) void gemm_zero_a(
    const float* __restrict__ x, const float* __restrict__ wg,
    float* __restrict__ P, float* __restrict__ gsum,
    int* __restrict__ ctr, float* __restrict__ out)
{
    const int tid = threadIdx.x;

    if (blockIdx.x >= 256) {
        const int zb = blockIdx.x - 256;
        zero_quads(out, 0, QA, 768, zb);
        if (zb == 0 && tid == 0) {
            out[OUT_ELEMS - 1] = 0.0f;  // odd tail element
            *ctr = 0;                   // handshake counter for k2
        }
        return;
    }

    __shared__ float xs[KC][132];
    __shared__ float wsh[KC][68];

    const int tile  = blockIdx.x >> 2;
    const int slice = blockIdx.x & 3;
    const int tok0 = tile * TOK_TILE;
    const int k0   = slice * KSLICE;

    if (blockIdx.x == 0 && tid < NEXP) gsum[tid] = 0.0f;

    const int tt = tid >> 4;
    const int te = tid & 15;

    float acc[8][4];
#pragma unroll
    for (int i = 0; i < 8; ++i)
#pragma unroll
        for (int j = 0; j < 4; ++j) acc[i][j] = 0.0f;

    const int we  = tid & 63;
    const int wkq = tid >> 6;

    float4 xv[4], wv[2];
#pragma unroll
    for (int r = 0; r < 4; ++r) {
        int idx = tid + 256 * r;
        int t = idx >> 3, kq = idx & 7;
        xv[r] = *(const float4*)(x + (size_t)(tok0 + t) * DIM + k0 + 4 * kq);
    }
    wv[0] = *(const float4*)(wg + (size_t)we * DIM + k0 + 4 * wkq);
    wv[1] = *(const float4*)(wg + (size_t)we * DIM + k0 + 4 * (wkq + 4));

    for (int kc = 0; kc < KSLICE; kc += KC) {
        __syncthreads();
#pragma unroll
        for (int r = 0; r < 4; ++r) {
            int idx = tid + 256 * r;
            int t = idx >> 3, k4 = (idx & 7) * 4;
            xs[k4 + 0][t] = xv[r].x; xs[k4 + 1][t] = xv[r].y;
            xs[k4 + 2][t] = xv[r].z; xs[k4 + 3][t] = xv[r].w;
        }
        {
            int k4 = 4 * wkq;
            wsh[k4 + 0][we] = wv[0].x; wsh[k4 + 1][we] = wv[0].y;
            wsh[k4 + 2][we] = wv[0].z; wsh[k4 + 3][we] = wv[0].w;
            int k4b = k4 + 16;
            wsh[k4b + 0][we] = wv[1].x; wsh[k4b + 1][we] = wv[1].y;
            wsh[k4b + 2][we] = wv[1].z; wsh[k4b + 3][we] = wv[1].w;
        }
        __syncthreads();
        if (kc + KC < KSLICE) {
#pragma unroll
            for (int r = 0; r < 4; ++r) {
                int idx = tid + 256 * r;
                int t = idx >> 3, kq = idx & 7;
                xv[r] = *(const float4*)(x + (size_t)(tok0 + t) * DIM + k0 + kc + KC + 4 * kq);
            }
            wv[0] = *(const float4*)(wg + (size_t)we * DIM + k0 + kc + KC + 4 * wkq);
            wv[1] = *(const float4*)(wg + (size_t)we * DIM + k0 + kc + KC + 4 * (wkq + 4));
        }
#pragma unroll 8
        for (int k = 0; k < KC; ++k) {
            float4 a0 = *(const float4*)&xs[k][8 * tt];
            float4 a1 = *(const float4*)&xs[k][8 * tt + 4];
            float4 b  = *(const float4*)&wsh[k][4 * te];
            const float* ap0 = &a0.x; const float* ap1 = &a1.x; const float* bp = &b.x;
#pragma unroll
            for (int i = 0; i < 4; ++i)
#pragma unroll
                for (int j = 0; j < 4; ++j) {
                    acc[i][j]     += ap0[i] * bp[j];
                    acc[i + 4][j] += ap1[i] * bp[j];
                }
        }
    }

#pragma unroll
    for (int i = 0; i < 8; ++i) {
        size_t off = ((size_t)slice * S_TOK + tok0 + 8 * tt + i) * NEXP + 4 * te;
        float4 v = { acc[i][0], acc[i][1], acc[i][2], acc[i][3] };
        *(float4*)(P + off) = v;
    }
}

// ---------------------------------------------------------------------------
// Kernel 2: block 0 = scanner (spin until 256 reducers release, then
//           ballot-rank scan -> loc[] + l_aux). Blocks 1-256 reduce 4 partials
//           + softmax + argmax + gsum, then __threadfence + atomicAdd(ctr).
//           Blocks 257-1024 zero region B. 256 threads/block.
// ---------------------------------------------------------------------------
__global__ __launch_bounds__(256) void reduce_scan_zero(
    const float* __restrict__ P,
    int* __restrict__ idx_out, float* __restrict__ gate_out,
    float* __restrict__ gsum, int* __restrict__ loc_out,
    int* __restrict__ ctr, float* __restrict__ out)
{
    const int tid = threadIdx.x;

    if (blockIdx.x >= 257) {
        zero_quads(out, QA, NQUAD, 768, blockIdx.x - 257);
        return;
    }

    if (blockIdx.x == 0) {
        // ----- scanner: wait for all 256 reduce blocks -----
        if (tid == 0) {
            while (atomicAdd(ctr, 0) < 256) __builtin_amdgcn_s_sleep(2);
        }
        __syncthreads();
        __threadfence();   // acquire: make reducers' idx/gate/gsum visible

        __shared__ int wavecnt[4][NEXP];
        __shared__ int basecnt[NEXP];
        const int lane = tid & 63;
        const int wv   = tid >> 6;

        if (tid < NEXP) basecnt[tid] = 0;
        __syncthreads();

        for (int it = 0; it < S_TOK / 256; ++it) {
            int tok = it * 256 + tid;
            int e = idx_out[tok];
            unsigned long long m = ~0ull, lm = ~0ull;
#pragma unroll
            for (int b = 0; b < 6; ++b) {
                unsigned long long bal = __ballot((e >> b) & 1);
                m  &= ((e >> b) & 1)    ? bal : ~bal;
                lm &= ((lane >> b) & 1) ? bal : ~bal;
            }
            int rank = __popcll(m & ((1ull << lane) - 1ull));
            wavecnt[wv][lane] = __popcll(lm);
            __syncthreads();
            int off = 0;
            for (int w = 0; w < wv; ++w) off += wavecnt[w][e];
            loc_out[tok] = basecnt[e] + off + rank;   // >= CAP means dropped
            __syncthreads();
            if (tid < NEXP) {
                int tot = 0;
#pragma unroll
                for (int w = 0; w < 4; ++w) tot += wavecnt[w][tid];
                basecnt[tid] += tot;
            }
            __syncthreads();
        }

        if (tid < NEXP) {
            float p = gsum[tid] * (float)basecnt[tid];
#pragma unroll
            for (int off = 32; off; off >>= 1) p += __shfl_xor(p, off, 64);
            if (tid == 0) out[0] = p * 9.5367431640625e-07f;  // 64/8192^2
        }
        return;
    }

    // ----- reducers: blocks 1..256 -----
    __shared__ float sme[NEXP];
    const int tok0 = (blockIdx.x - 1) * 32;
    const int ty = tid >> 5;
    const int tx = tid & 31;
    const int t0 = ty * 4;
    const int e0 = tx * 2;

    if (tid < NEXP) sme[tid] = 0.0f;
    __syncthreads();

    float gm0 = 0.0f, gm1 = 0.0f;
#pragma unroll
    for (int i = 0; i < 4; ++i) {
        int tok = tok0 + t0 + i;
        float l0 = 0.0f, l1 = 0.0f;
#pragma unroll
        for (int s = 0; s < NSLICE; ++s) {
            float2 p = *(const float2*)&P[((size_t)s * S_TOK + tok) * NEXP + e0];
            l0 += p.x; l1 += p.y;
        }
        float v; int ix;
        if (l1 > l0) { v = l1; ix = e0 + 1; } else { v = l0; ix = e0; }
#pragma unroll
        for (int off = 16; off; off >>= 1) {
            float ov = __shfl_xor(v, off, 32);
            int   oi = __shfl_xor(ix, off, 32);
            if (ov > v || (ov == v && oi < ix)) { v = ov; ix = oi; }
        }
        float z0 = __expf(l0 - v), z1 = __expf(l1 - v);
        float zs = z0 + z1;
#pragma unroll
        for (int off = 16; off; off >>= 1) zs += __shfl_xor(zs, off, 32);
        float inv = 1.0f / zs;
        gm0 += z0 * inv; gm1 += z1 * inv;
        if (tx == 0) {
            idx_out[tok]  = ix;
            gate_out[tok] = inv;   // winning gate = exp(0)/zs
        }
    }
    atomicAdd(&sme[e0], gm0);
    atomicAdd(&sme[e0 + 1], gm1);
    __syncthreads();
    if (tid < NEXP) atomicAdd(&gsum[tid], sme[tid]);

    // release: make idx/gate stores visible at agent scope, then signal
    __threadfence();
    __syncthreads();
    if (tid == 0) atomicAdd(ctr, 1);
}

// ---------------------------------------------------------------------------
// Kernel 3: sparse scatter into fully-zeroed output. One token per thread.
// ---------------------------------------------------------------------------
__global__ __launch_bounds__(256) void scatter_kernel(
    const int* __restrict__ idx, const float* __restrict__ gate,
    const int* __restrict__ loc, float* __restrict__ out)
{
    int t = blockIdx.x * 256 + threadIdx.x;
    int l = loc[t];
    if (l < CAP) {
        size_t base = 1 + (size_t)t * (NEXP * CAP) + (size_t)idx[t] * CAP + l;
        out[base] = gate[t];              // combine_weights
        out[base + COMB_ELEMS] = 1.0f;    // dispatch_mask
    }
}

extern "C" void kernel_launch(void* const* d_in, const int* in_sizes, int n_in,
                              void* d_out, int out_size, void* d_ws, size_t ws_size,
                              hipStream_t stream) {
    const float* x  = (const float*)d_in[0];   // [8192, 2048] fp32
    const float* wg = (const float*)d_in[1];   // [64, 2048] fp32
    float* out = (float*)d_out;

    // ws layout
    int*   idx  = (int*)d_ws;                             // 32 KB
    float* gate = (float*)((char*)d_ws + 32768);          // 32 KB
    float* gsum = (float*)((char*)d_ws + 65536);          // 256 B
    int*   ctr  = (int*)((char*)d_ws + 65792);            // 4 B handshake
    int*   loc  = (int*)((char*)d_ws + 66560);            // 32 KB
    float* P    = (float*)((char*)d_ws + 262144);         // 8 MB partials

    gemm_zero_a<<<1024, 256, 0, stream>>>(x, wg, P, gsum, ctr, out);
    reduce_scan_zero<<<1025, 256, 0, stream>>>(P, idx, gate, gsum, loc, ctr, out);
    scatter_kernel<<<S_TOK / 256, 256, 0, stream>>>(idx, gate, loc, out);
}

// Round 2
// 601.942 us; speedup vs baseline: 1.0426x; 1.0426x over previous
//
#include <hip/hip_runtime.h>
#include <cstdint>
#include <cstddef>

// Top-1 MoE gate. s=8192, e=64, d=2048, cap=128.
// d_out (float32): [l_aux(1), combine(8192*64*128), mask(8192*64*128)]
// 3-kernel pipeline, fence-free (kernel boundaries provide all ordering):
//   k1 gemm_zero_a  : 256 split-K GEMM blocks + 768 blocks zero region A (~236 MB)
//   k2 reduce_zero_b: 256 reduce blocks (softmax/argmax/gsum) + 768 zero B (~300 MB)
//   k3 scan_scatter : single 1024-thread block: ballot-rank scan -> loc in
//                     registers, immediate scatter (2 stores/surviving token),
//                     l_aux. No loc[] round-trip, no 4th launch.
// HBM balance: k1 ~ 64(x)+8(P)+236(zeros) = 308 MB, k2 ~ 8(P)+300(zeros) = 308 MB.

#define S_TOK 8192
#define NEXP 64
#define DIM 2048
#define CAP 128
#define COMB_ELEMS ((size_t)S_TOK * NEXP * CAP)   // 67108864
#define OUT_ELEMS (1 + 2 * COMB_ELEMS)            // 134217729
#define NQUAD ((size_t)(OUT_ELEMS / 4))           // 33554432 quads cover all but last elem

// Split so k1 total HBM bytes ~= k2 total HBM bytes (see header comment).
#define QA ((size_t)14777216)   // region A: [0, QA)     ~236.4 MB (k1)
                                // region B: [QA, NQUAD) ~300.4 MB (k2)

#define TOK_TILE 128
#define NSLICE 4
#define KSLICE (DIM / NSLICE)   // 512
#define KC 32

__device__ __forceinline__ void zero_quads(float* __restrict__ out,
                                           size_t q_begin, size_t q_end,
                                           int nblocks, int bid) {
    const float4 z = { 0.0f, 0.0f, 0.0f, 0.0f };
    size_t stride = (size_t)nblocks * blockDim.x;
    for (size_t q = q_begin + (size_t)bid * blockDim.x + threadIdx.x;
         q < q_end; q += stride)
        *(float4*)(out + 4 * q) = z;
}

// ---------------------------------------------------------------------------
// Kernel 1: split-K logits GEMM (blocks 0-255) + zero region A (blocks 256-1023)
// ---------------------------------------------------------------------------
__global__ __launch_bounds__(256, 4) void gemm_zero_a(
    const float* __restrict__ x, const float* __restrict__ wg,
    float* __restrict__ P, float* __restrict__ gsum,
    float* __restrict__ out)
{
    const int tid = threadIdx.x;

    if (blockIdx.x >= 256) {
        const int zb = blockIdx.x - 256;
        zero_quads(out, 0, QA, 768, zb);
        if (zb == 0 && tid == 0) out[OUT_ELEMS - 1] = 0.0f;  // odd tail element
        return;
    }

    __shared__ float xs[KC][132];
    __shared__ float wsh[KC][68];

    const int tile  = blockIdx.x >> 2;
    const int slice = blockIdx.x & 3;
    const int tok0 = tile * TOK_TILE;
    const int k0   = slice * KSLICE;

    if (blockIdx.x == 0 && tid < NEXP) gsum[tid] = 0.0f;

    const int tt = tid >> 4;
    const int te = tid & 15;

    float acc[8][4];
#pragma unroll
    for (int i = 0; i < 8; ++i)
#pragma unroll
        for (int j = 0; j < 4; ++j) acc[i][j] = 0.0f;

    const int we  = tid & 63;
    const int wkq = tid >> 6;

    float4 xv[4], wv[2];
#pragma unroll
    for (int r = 0; r < 4; ++r) {
        int idx = tid + 256 * r;
        int t = idx >> 3, kq = idx & 7;
        xv[r] = *(const float4*)(x + (size_t)(tok0 + t) * DIM + k0 + 4 * kq);
    }
    wv[0] = *(const float4*)(wg + (size_t)we * DIM + k0 + 4 * wkq);
    wv[1] = *(const float4*)(wg + (size_t)we * DIM + k0 + 4 * (wkq + 4));

    for (int kc = 0; kc < KSLICE; kc += KC) {
        __syncthreads();
#pragma unroll
        for (int r = 0; r < 4; ++r) {
            int idx = tid + 256 * r;
            int t = idx >> 3, k4 = (idx & 7) * 4;
            xs[k4 + 0][t] = xv[r].x; xs[k4 + 1][t] = xv[r].y;
            xs[k4 + 2][t] = xv[r].z; xs[k4 + 3][t] = xv[r].w;
        }
        {
            int k4 = 4 * wkq;
            wsh[k4 + 0][we] = wv[0].x; wsh[k4 + 1][we] = wv[0].y;
            wsh[k4 + 2][we] = wv[0].z; wsh[k4 + 3][we] = wv[0].w;
            int k4b = k4 + 16;
            wsh[k4b + 0][we] = wv[1].x; wsh[k4b + 1][we] = wv[1].y;
            wsh[k4b + 2][we] = wv[1].z; wsh[k4b + 3][we] = wv[1].w;
        }
        __syncthreads();
        if (kc + KC < KSLICE) {
#pragma unroll
            for (int r = 0; r < 4; ++r) {
                int idx = tid + 256 * r;
                int t = idx >> 3, kq = idx & 7;
                xv[r] = *(const float4*)(x + (size_t)(tok0 + t) * DIM + k0 + kc + KC + 4 * kq);
            }
            wv[0] = *(const float4*)(wg + (size_t)we * DIM + k0 + kc + KC + 4 * wkq);
            wv[1] = *(const float4*)(wg + (size_t)we * DIM + k0 + kc + KC + 4 * (wkq + 4));
        }
#pragma unroll 8
        for (int k = 0; k < KC; ++k) {
            float4 a0 = *(const float4*)&xs[k][8 * tt];
            float4 a1 = *(const float4*)&xs[k][8 * tt + 4];
            float4 b  = *(const float4*)&wsh[k][4 * te];
            const float* ap0 = &a0.x; const float* ap1 = &a1.x; const float* bp = &b.x;
#pragma unroll
            for (int i = 0; i < 4; ++i)
#pragma unroll
                for (int j = 0; j < 4; ++j) {
                    acc[i][j]     += ap0[i] * bp[j];
                    acc[i + 4][j] += ap1[i] * bp[j];
                }
        }
    }

#pragma unroll
    for (int i = 0; i < 8; ++i) {
        size_t off = ((size_t)slice * S_TOK + tok0 + 8 * tt + i) * NEXP + 4 * te;
        float4 v = { acc[i][0], acc[i][1], acc[i][2], acc[i][3] };
        *(float4*)(P + off) = v;
    }
}

// ---------------------------------------------------------------------------
// Kernel 2: reduce 4 partials + softmax + argmax + gsum (blocks 0-255)
//           + zero region B (blocks 256-1023)
// ---------------------------------------------------------------------------
__global__ __launch_bounds__(256) void reduce_zero_b(
    const float* __restrict__ P,
    int* __restrict__ idx_out, float* __restrict__ gate_out,
    float* __restrict__ gsum, float* __restrict__ out)
{
    const int tid = threadIdx.x;

    if (blockIdx.x >= 256) {
        zero_quads(out, QA, NQUAD, 768, blockIdx.x - 256);
        return;
    }

    __shared__ float sme[NEXP];
    const int tok0 = blockIdx.x * 32;
    const int ty = tid >> 5;
    const int tx = tid & 31;
    const int t0 = ty * 4;
    const int e0 = tx * 2;

    if (tid < NEXP) sme[tid] = 0.0f;
    __syncthreads();

    float gm0 = 0.0f, gm1 = 0.0f;
#pragma unroll
    for (int i = 0; i < 4; ++i) {
        int tok = tok0 + t0 + i;
        float l0 = 0.0f, l1 = 0.0f;
#pragma unroll
        for (int s = 0; s < NSLICE; ++s) {
            float2 p = *(const float2*)&P[((size_t)s * S_TOK + tok) * NEXP + e0];
            l0 += p.x; l1 += p.y;
        }
        float v; int ix;
        if (l1 > l0) { v = l1; ix = e0 + 1; } else { v = l0; ix = e0; }
#pragma unroll
        for (int off = 16; off; off >>= 1) {
            float ov = __shfl_xor(v, off, 32);
            int   oi = __shfl_xor(ix, off, 32);
            if (ov > v || (ov == v && oi < ix)) { v = ov; ix = oi; }
        }
        float z0 = __expf(l0 - v), z1 = __expf(l1 - v);
        float zs = z0 + z1;
#pragma unroll
        for (int off = 16; off; off >>= 1) zs += __shfl_xor(zs, off, 32);
        float inv = 1.0f / zs;
        gm0 += z0 * inv; gm1 += z1 * inv;
        if (tx == 0) {
            idx_out[tok]  = ix;
            gate_out[tok] = inv;   // winning gate = exp(0)/zs
        }
    }
    atomicAdd(&sme[e0], gm0);
    atomicAdd(&sme[e0 + 1], gm1);
    __syncthreads();
    if (tid < NEXP) atomicAdd(&gsum[tid], sme[tid]);
}

// ---------------------------------------------------------------------------
// Kernel 3: single 1024-thread block. Ballot-rank scan -> loc in registers,
// immediate scatter into pre-zeroed output, then l_aux. Kernel boundary
// guarantees all zeros from k1/k2 landed before these stores.
// ---------------------------------------------------------------------------
__global__ __launch_bounds__(1024) void scan_scatter(
    const int* __restrict__ idx, const float* __restrict__ gate,
    const float* __restrict__ gsum, float* __restrict__ out)
{
    const int tid = threadIdx.x;

    __shared__ int wavecnt[16][NEXP];
    __shared__ int basecnt[NEXP];
    const int lane = tid & 63;
    const int wv   = tid >> 6;

    if (tid < NEXP) basecnt[tid] = 0;
    __syncthreads();

    for (int it = 0; it < S_TOK / 1024; ++it) {
        int tok = it * 1024 + tid;
        int e = idx[tok];
        float g = gate[tok];          // issue early; used only if not dropped
        unsigned long long m = ~0ull, lm = ~0ull;
#pragma unroll
        for (int b = 0; b < 6; ++b) {
            unsigned long long bal = __ballot((e >> b) & 1);
            m  &= ((e >> b) & 1)    ? bal : ~bal;
            lm &= ((lane >> b) & 1) ? bal : ~bal;
        }
        int rank = __popcll(m & ((1ull << lane) - 1ull));
        wavecnt[wv][lane] = __popcll(lm);
        __syncthreads();
        int off = 0;
        for (int w = 0; w < wv; ++w) off += wavecnt[w][e];
        int l = basecnt[e] + off + rank;          // >= CAP means dropped
        if (l < CAP) {
            size_t base = 1 + (size_t)tok * (NEXP * CAP) + (size_t)e * CAP + l;
            out[base] = g;                        // combine_weights
            out[base + COMB_ELEMS] = 1.0f;        // dispatch_mask
        }
        __syncthreads();
        if (tid < NEXP) {
            int tot = 0;
#pragma unroll
            for (int w = 0; w < 16; ++w) tot += wavecnt[w][tid];
            basecnt[tid] += tot;
        }
        __syncthreads();
    }

    if (tid < NEXP) {
        float p = gsum[tid] * (float)basecnt[tid];
#pragma unroll
        for (int off = 32; off; off >>= 1) p += __shfl_xor(p, off, 64);
        if (tid == 0) out[0] = p * 9.5367431640625e-07f;  // 64/8192^2
    }
}

extern "C" void kernel_launch(void* const* d_in, const int* in_sizes, int n_in,
                              void* d_out, int out_size, void* d_ws, size_t ws_size,
                              hipStream_t stream) {
    const float* x  = (const float*)d_in[0];   // [8192, 2048] fp32
    const float* wg = (const float*)d_in[1];   // [64, 2048] fp32
    float* out = (float*)d_out;

    // ws layout
    int*   idx  = (int*)d_ws;                             // 32 KB
    float* gate = (float*)((char*)d_ws + 32768);          // 32 KB
    float* gsum = (float*)((char*)d_ws + 65536);          // 256 B
    float* P    = (float*)((char*)d_ws + 262144);         // 8 MB partials

    gemm_zero_a<<<1024, 256, 0, stream>>>(x, wg, P, gsum, out);
    reduce_zero_b<<<1024, 256, 0, stream>>>(P, idx, gate, gsum, out);
    scan_scatter<<<1, 1024, 0, stream>>>(idx, gate, gsum, out);
}